// Round 11
// baseline (149.648 us; speedup 1.0000x reference)
//
#include <hip/hip_runtime.h>
#include <math.h>

#define BATCH 524288
#define NJ 12

// ws float layout:
//   [0..239]    joint consts (12 x 20)
//   [240..251]  T0 (R row-major 9, p 3)
//   [256..5631]     21 weight frags x 64 lanes x uint4 (h0..h3|l0..l3 packed f16, lo UNSCALED)
//   [5632..8191]    10 bias frags x 64 lanes x f32x4
#define WOFF 256
#define BOFF 5632

typedef _Float16 half4 __attribute__((ext_vector_type(4)));
typedef _Float16 half2t __attribute__((ext_vector_type(2)));
typedef float f32x4 __attribute__((ext_vector_type(4)));

#define MFMA16(a, b, c) __builtin_amdgcn_mfma_f32_16x16x16f16((a), (b), (c), 0, 0, 0)

__device__ __forceinline__ f32x4 ld4(const float* p) { return *(const f32x4*)p; }

// hi = RTZ f16 of v; lo = f16(v - hi), UNSCALED (residual below f16-normal is
// flushed with <=6e-5 abs error — inside budget; measured absmax 0.0078).
__device__ __forceinline__ void split4(f32x4 v, half4& h, half4& l) {
    half2t ha = __builtin_bit_cast(half2t, __builtin_amdgcn_cvt_pkrtz(v[0], v[1]));
    half2t hb = __builtin_bit_cast(half2t, __builtin_amdgcn_cvt_pkrtz(v[2], v[3]));
    float r0 = v[0] - (float)ha[0];
    float r1 = v[1] - (float)ha[1];
    float r2 = v[2] - (float)hb[0];
    float r3 = v[3] - (float)hb[1];
    half2t la = __builtin_bit_cast(half2t, __builtin_amdgcn_cvt_pkrtz(r0, r1));
    half2t lb = __builtin_bit_cast(half2t, __builtin_amdgcn_cvt_pkrtz(r2, r3));
    h = half4{ha[0], ha[1], hb[0], hb[1]};
    l = half4{la[0], la[1], lb[0], lb[1]};
}

__device__ __forceinline__ f32x4 relu4(f32x4 v) {
    f32x4 r;
#pragma unroll
    for (int i = 0; i < 4; i++) r[i] = fmaxf(v[i], 0.0f);
    return r;
}

__device__ __forceinline__ void unpack_frag(uint4 u, half4& h, half4& l) {
    uint2 a = make_uint2(u.x, u.y), b = make_uint2(u.z, u.w);
    h = __builtin_bit_cast(half4, a);
    l = __builtin_bit_cast(half4, b);
}

__global__ void precompute_kernel(const float* __restrict__ twist,
                                  const float* __restrict__ init_p,
                                  const float* __restrict__ init_rpy,
                                  const float* __restrict__ W1, const float* __restrict__ b1,
                                  const float* __restrict__ W2, const float* __restrict__ b2,
                                  const float* __restrict__ W3, const float* __restrict__ b3,
                                  const float* __restrict__ W4, const float* __restrict__ b4,
                                  const float* __restrict__ W5, const float* __restrict__ b5,
                                  float* __restrict__ ws) {
    const int lane = threadIdx.x;       // 64 threads
    const int qd = lane >> 4, l16 = lane & 15;
    const f32x4 FZ = {0.f, 0.f, 0.f, 0.f};

    // ---- joint invariants + T0 (threads 0..12) ----
    if (lane < NJ) {
        int j = lane;
        float rho0 = twist[j*6+0], rho1 = twist[j*6+1], rho2 = twist[j*6+2];
        float w0   = twist[j*6+3], w1   = twist[j*6+4], w2   = twist[j*6+5];
        float wn = sqrtf(w0*w0 + w1*w1 + w2*w2 + 1e-12f);
        float inv = 1.0f / wn;
        float u0 = w0*inv, u1 = w1*inv, u2 = w2*inv;
        float ru0 = rho0*inv, ru1 = rho1*inv, ru2 = rho2*inv;
        float kru0 = u1*ru2 - u2*ru1;
        float kru1 = u2*ru0 - u0*ru2;
        float kru2 = u0*ru1 - u1*ru0;
        float ud = u0*ru0 + u1*ru1 + u2*ru2;
        float* o = ws + j*20;
        o[0] = wn;  o[1] = u0;  o[2] = u1;  o[3] = u2;
        o[4] = ru0; o[5] = ru1; o[6] = ru2;
        o[7] = kru0; o[8] = kru1; o[9] = kru2;
        o[10] = u0*ud - ru0; o[11] = u1*ud - ru1; o[12] = u2*ud - ru2;
        o[13] = u0*u0; o[14] = u0*u1; o[15] = u0*u2;
        o[16] = u1*u1; o[17] = u1*u2; o[18] = u2*u2;
    } else if (lane == NJ) {
        float r = init_rpy[0], p = init_rpy[1], y = init_rpy[2];
        float cr = cosf(r), sr = sinf(r);
        float cp = cosf(p), sp = sinf(p);
        float cy = cosf(y), sy = sinf(y);
        float* o = ws + NJ*20;
        o[0] = cy*cp; o[1] = cy*sp*sr - sy*cr; o[2] = cy*sp*cr + sy*sr;
        o[3] = sy*cp; o[4] = sy*sp*sr + cy*cr; o[5] = sy*sp*cr - cy*sr;
        o[6] = -sp;   o[7] = cp*sr;            o[8] = cp*cr;
        o[9] = init_p[0]; o[10] = init_p[1]; o[11] = init_p[2];
    }

    // ---- weight fragments (hi/lo split, lo UNSCALED residual) ----
    uint4* wf = (uint4*)(ws + WOFF);
    f32x4* bf = (f32x4*)(ws + BOFF);

    auto pack = [&](f32x4 w) -> uint4 {
        half4 h, l;
#pragma unroll
        for (int i = 0; i < 4; i++) {
            _Float16 hi = (_Float16)w[i];
            h[i] = hi;
            l[i] = (_Float16)(w[i] - (float)hi);
        }
        uint2 uh = __builtin_bit_cast(uint2, h);
        uint2 ul = __builtin_bit_cast(uint2, l);
        return make_uint4(uh.x, uh.y, ul.x, ul.y);
    };

    // f0: a1 (K=4 padded to 16 -> only qd==0 valid; rows k>=4 ZEROED so the
    // B-side x fragment never needs masking: 0 * finite = 0)
    {
        f32x4 w = ld4(W1 + l16*4);
        wf[0*64 + lane] = pack(qd == 0 ? w : FZ);
    }
    // f1,2: a2[ot]
    for (int ot = 0; ot < 2; ot++)
        wf[(1+ot)*64 + lane] = pack(ld4(W2 + (ot*16 + l16)*16 + 4*qd));
    // f3..10: a3[ot][kc]
    for (int ot = 0; ot < 4; ot++)
        for (int kc = 0; kc < 2; kc++)
            wf[(3 + ot*2 + kc)*64 + lane] = pack(ld4(W3 + (ot*16 + l16)*32 + kc*16 + 4*qd));
    // f11..18: a4[ot][kc]
    for (int ot = 0; ot < 2; ot++)
        for (int kc = 0; kc < 4; kc++)
            wf[(11 + ot*4 + kc)*64 + lane] = pack(ld4(W4 + (ot*16 + l16)*64 + kc*16 + 4*qd));
    // f19,20: a5[kc] (rows >=12 zeroed)
    {
        int r5 = (l16 < 12) ? l16 : 11;
        for (int kc = 0; kc < 2; kc++) {
            f32x4 w = ld4(W5 + r5*32 + kc*16 + 4*qd);
            wf[(19+kc)*64 + lane] = pack(l16 < 12 ? w : FZ);
        }
    }
    // bias frags
    bf[0*64 + lane] = ld4(b1 + 4*qd);
    for (int ot = 0; ot < 2; ot++) bf[(1+ot)*64 + lane] = ld4(b2 + ot*16 + 4*qd);
    for (int ot = 0; ot < 4; ot++) bf[(3+ot)*64 + lane] = ld4(b3 + ot*16 + 4*qd);
    for (int ot = 0; ot < 2; ot++) bf[(7+ot)*64 + lane] = ld4(b4 + ot*16 + 4*qd);
    {
        f32x4 w = ld4(b5 + ((qd < 3) ? 4*qd : 8));
        bf[9*64 + lane] = (qd < 3) ? w : FZ;
    }
}

// (256,3): cap 168 unified. The compiler splits a capped budget ~50/50 arch/AGPR
// (R4 cap128->VGPR64, R8/R9 cap168->VGPR84), so the ARCH live set must fit in 84.
// This variant is single-chain (no 2-elem ILP), no prefetch, no B-masking —
// arch demand ~80-90. Tripwire: WRITE_SIZE > 50 MB => spill => revert to R10.
__global__ __launch_bounds__(256, 3) void fk_kernel(
    const float* __restrict__ mc,
    const float* __restrict__ ws,
    float* __restrict__ out) {
    const int tid = threadIdx.x;
    const int wv = tid >> 6, lane = tid & 63;
    const int qd = lane >> 4, l16 = lane & 15;
    const int wave_base = (blockIdx.x * 4 + wv) * 64;

    const uint4* wf = (const uint4*)(ws + WOFF);
    const f32x4* bf = (const f32x4*)(ws + BOFF);

    // LDS: ALL 21 weight frags (21 KB) + per-wave q buffer (stride 13, ~13 KB)
    __shared__ __align__(16) uint4 wstage[21*64];
    __shared__ float qbuf[4][64*13];

    // stage weight frags once per block
    for (int i = tid; i < 21*64; i += 256) wstage[i] = wf[i];

    __syncthreads();

#pragma unroll 1
    for (int e = 0; e < 4; e++) {
        const int ce = wave_base + e*16 + l16;

        // Layer 1: 4 -> 16. x B-frag needs no qd masking: A rows k>=4 are zero.
        f32x4 xv = ld4(mc + (size_t)ce * 4);
        half4 bxh, bxl; split4(xv, bxh, bxl);
        half4 g1h, g1l;
        {
            half4 wh, wl; unpack_frag(wstage[0*64 + lane], wh, wl);
            f32x4 acc = bf[0*64 + lane];
            acc = MFMA16(wh, bxh, acc);
            acc = MFMA16(wh, bxl, acc);
            acc = MFMA16(wl, bxh, acc);
            split4(relu4(acc), g1h, g1l);
        }

        // Layer 2: 16 -> 32
        half4 g2h[2], g2l[2];
#pragma unroll
        for (int ot = 0; ot < 2; ot++) {
            half4 wh, wl; unpack_frag(wstage[(1+ot)*64 + lane], wh, wl);
            f32x4 acc = bf[(1+ot)*64 + lane];
            acc = MFMA16(wh, g1h, acc);
            acc = MFMA16(wh, g1l, acc);
            acc = MFMA16(wl, g1h, acc);
            split4(relu4(acc), g2h[ot], g2l[ot]);
        }

        // Layer 3: 32 -> 64
        half4 g3h[4], g3l[4];
#pragma unroll
        for (int ot = 0; ot < 4; ot++) {
            f32x4 acc = bf[(3+ot)*64 + lane];
#pragma unroll
            for (int kc = 0; kc < 2; kc++) {
                half4 wh, wl; unpack_frag(wstage[(3 + ot*2 + kc)*64 + lane], wh, wl);
                acc = MFMA16(wh, g2h[kc], acc);
                acc = MFMA16(wh, g2l[kc], acc);
                acc = MFMA16(wl, g2h[kc], acc);
            }
            split4(relu4(acc), g3h[ot], g3l[ot]);
        }

        // Layer 4: 64 -> 32
        half4 g4h[2], g4l[2];
#pragma unroll
        for (int ot = 0; ot < 2; ot++) {
            f32x4 acc = bf[(7+ot)*64 + lane];
#pragma unroll
            for (int kc = 0; kc < 4; kc++) {
                half4 wh, wl; unpack_frag(wstage[(11 + ot*4 + kc)*64 + lane], wh, wl);
                acc = MFMA16(wh, g3h[kc], acc);
                acc = MFMA16(wh, g3l[kc], acc);
                acc = MFMA16(wl, g3h[kc], acc);
            }
            split4(relu4(acc), g4h[ot], g4l[ot]);
        }

        // Layer 5: 32 -> 12. C rows are 4*qd+i: qd 0..2 hold q[0..11]; qd==3 holds
        // garbage rows 12..15 — with stride-13 qbuf its store would clobber the
        // next row's q[0..2], so mask it off.
        {
            f32x4 acc = bf[9*64 + lane];
#pragma unroll
            for (int kc = 0; kc < 2; kc++) {
                half4 wh, wl; unpack_frag(wstage[(19+kc)*64 + lane], wh, wl);
                acc = MFMA16(wh, g4h[kc], acc);
                acc = MFMA16(wh, g4l[kc], acc);
                acc = MFMA16(wl, g4h[kc], acc);
            }
            f32x4 qv = relu4(acc);
            if (qd < 3) {
                float* qb = &qbuf[wv][(e*16 + l16)*13 + 4*qd];
                qb[0] = qv[0]; qb[1] = qv[1]; qb[2] = qv[2]; qb[3] = qv[3];
            }
        }
    }

    // q writes are wave-private; drain LDS then redistribute
    asm volatile("s_waitcnt lgkmcnt(0)" ::: "memory");

    float qq[12];
#pragma unroll
    for (int j = 0; j < 12; j++) qq[j] = qbuf[wv][lane*13 + j];

    // ---------- FK chain (fp32) ----------
    const float* jc = ws;
    float M00 = 1.f, M01 = 0.f, M02 = 0.f;
    float M10 = 0.f, M11 = 1.f, M12 = 0.f;
    float M20 = 0.f, M21 = 0.f, M22 = 1.f;
    float v0 = 0.f, v1 = 0.f, v2 = 0.f;

#pragma unroll
    for (int j = 0; j < NJ; j++) {
        const float* c = jc + j*20;
        float wn = c[0];
        float u0 = c[1], u1 = c[2], u2 = c[3];
        float ru0 = c[4], ru1 = c[5], ru2 = c[6];
        float kru0 = c[7], kru1 = c[8], kru2 = c[9];
        float k2ru0 = c[10], k2ru1 = c[11], k2ru2 = c[12];
        float uu00 = c[13], uu01 = c[14], uu02 = c[15];
        float uu11 = c[16], uu12 = c[17], uu22 = c[18];

        float th = qq[j] * wn;
        float s = __sinf(th);
        float cth = __cosf(th);
        float cc = 1.0f - cth;
        float t = th - s;

        float R00 = 1.0f + cc*(uu00 - 1.0f);
        float R01 = cc*uu01 - s*u2;
        float R02 = cc*uu02 + s*u1;
        float R10 = cc*uu01 + s*u2;
        float R11 = 1.0f + cc*(uu11 - 1.0f);
        float R12 = cc*uu12 - s*u0;
        float R20 = cc*uu02 - s*u1;
        float R21 = cc*uu12 + s*u0;
        float R22 = 1.0f + cc*(uu22 - 1.0f);

        float p0 = th*ru0 + cc*kru0 + t*k2ru0;
        float p1 = th*ru1 + cc*kru1 + t*k2ru1;
        float p2 = th*ru2 + cc*kru2 + t*k2ru2;

        float n00 = M00*R00 + M01*R10 + M02*R20;
        float n01 = M00*R01 + M01*R11 + M02*R21;
        float n02 = M00*R02 + M01*R12 + M02*R22;
        float n10 = M10*R00 + M11*R10 + M12*R20;
        float n11 = M10*R01 + M11*R11 + M12*R21;
        float n12 = M10*R02 + M11*R12 + M12*R22;
        float n20 = M20*R00 + M21*R10 + M22*R20;
        float n21 = M20*R01 + M21*R11 + M22*R21;
        float n22 = M20*R02 + M21*R12 + M22*R22;
        v0 += M00*p0 + M01*p1 + M02*p2;
        v1 += M10*p0 + M11*p1 + M12*p2;
        v2 += M20*p0 + M21*p1 + M22*p2;
        M00 = n00; M01 = n01; M02 = n02;
        M10 = n10; M11 = n11; M12 = n12;
        M20 = n20; M21 = n21; M22 = n22;
    }

    const float* t0 = jc + NJ*20;
    float A00 = t0[0], A01 = t0[1], A02 = t0[2];
    float A10 = t0[3], A11 = t0[4], A12 = t0[5];
    float A20 = t0[6], A21 = t0[7], A22 = t0[8];
    float P0  = t0[9], P1  = t0[10], P2 = t0[11];

    float F00 = M00*A00 + M01*A10 + M02*A20;
    float F01 = M00*A01 + M01*A11 + M02*A21;
    float F02 = M00*A02 + M01*A12 + M02*A22;
    float F10 = M10*A00 + M11*A10 + M12*A20;
    float F11 = M10*A01 + M11*A11 + M12*A21;
    float F12 = M10*A02 + M11*A12 + M12*A22;
    float F20 = M20*A00 + M21*A10 + M22*A20;
    float F21 = M20*A01 + M21*A11 + M22*A21;
    float F22 = M20*A02 + M21*A12 + M22*A22;
    float Fv0 = M00*P0 + M01*P1 + M02*P2 + v0;
    float Fv1 = M10*P0 + M11*P1 + M12*P2 + v1;
    float Fv2 = M20*P0 + M21*P1 + M22*P2 + v2;

    const int eo = wave_base + lane;
    float4* o4 = (float4*)(out + (size_t)eo * 16);
    o4[0] = make_float4(F00, F01, F02, Fv0);
    o4[1] = make_float4(F10, F11, F12, Fv1);
    o4[2] = make_float4(F20, F21, F22, Fv2);
    o4[3] = make_float4(0.f, 0.f, 0.f, 1.f);
}

extern "C" void kernel_launch(void* const* d_in, const int* in_sizes, int n_in,
                              void* d_out, int out_size, void* d_ws, size_t ws_size,
                              hipStream_t stream) {
    const float* mc      = (const float*)d_in[0];
    const float* W1      = (const float*)d_in[1];
    const float* b1      = (const float*)d_in[2];
    const float* W2      = (const float*)d_in[3];
    const float* b2      = (const float*)d_in[4];
    const float* W3      = (const float*)d_in[5];
    const float* b3      = (const float*)d_in[6];
    const float* W4      = (const float*)d_in[7];
    const float* b4      = (const float*)d_in[8];
    const float* W5      = (const float*)d_in[9];
    const float* b5      = (const float*)d_in[10];
    const float* twist   = (const float*)d_in[11];
    const float* init_p  = (const float*)d_in[12];
    const float* init_rpy= (const float*)d_in[13];
    float* out = (float*)d_out;
    float* ws  = (float*)d_ws;

    precompute_kernel<<<1, 64, 0, stream>>>(twist, init_p, init_rpy,
                                            W1, b1, W2, b2, W3, b3, W4, b4, W5, b5, ws);
    fk_kernel<<<BATCH / 256, 256, 0, stream>>>(mc, ws, out);
}

// Round 12
// 142.100 us; speedup vs baseline: 1.0531x; 1.0531x over previous
//
#include <hip/hip_runtime.h>
#include <math.h>

#define BATCH 524288
#define NJ 12

// ws float layout:
//   [0..239]    joint consts (12 x 20)
//   [240..251]  T0 (R row-major 9, p 3)
//   [256..5631]     21 weight frags x 64 lanes x uint4 (h0..h3|l0..l3 packed f16, lo UNSCALED)
//   [5632..8191]    10 bias frags x 64 lanes x f32x4
#define WOFF 256
#define BOFF 5632

typedef _Float16 half4 __attribute__((ext_vector_type(4)));
typedef _Float16 half8 __attribute__((ext_vector_type(8)));
typedef _Float16 half2t __attribute__((ext_vector_type(2)));
typedef float f32x4 __attribute__((ext_vector_type(4)));

// K=32 MFMA: A,B = 8 f16 (4 VGPRs). k-permutation: lane qd, slot j:
//   j<4 -> (logical k = 4*qd+j, HI part), j>=4 -> (logical k = 4*qd+j-4, LO part)
// A-frag normal = [wh|wl] (the packed uint4 as-is), swapped = [wl|wh].
// B-frag = [gh|gl] = previous layer's C split in place (chaining preserved).
#define MFMA32(a, b, c) __builtin_amdgcn_mfma_f32_16x16x32_f16((a), (b), (c), 0, 0, 0)

__device__ __forceinline__ f32x4 ld4(const float* p) { return *(const f32x4*)p; }

// hi = RTZ f16 of v; lo = f16(v - hi), UNSCALED. Returns packed half8 [h|l].
__device__ __forceinline__ half8 split8(f32x4 v) {
    half2t ha = __builtin_bit_cast(half2t, __builtin_amdgcn_cvt_pkrtz(v[0], v[1]));
    half2t hb = __builtin_bit_cast(half2t, __builtin_amdgcn_cvt_pkrtz(v[2], v[3]));
    float r0 = v[0] - (float)ha[0];
    float r1 = v[1] - (float)ha[1];
    float r2 = v[2] - (float)hb[0];
    float r3 = v[3] - (float)hb[1];
    half2t la = __builtin_bit_cast(half2t, __builtin_amdgcn_cvt_pkrtz(r0, r1));
    half2t lb = __builtin_bit_cast(half2t, __builtin_amdgcn_cvt_pkrtz(r2, r3));
    return half8{ha[0], ha[1], hb[0], hb[1], la[0], la[1], lb[0], lb[1]};
}

__device__ __forceinline__ f32x4 relu4(f32x4 v) {
    f32x4 r;
#pragma unroll
    for (int i = 0; i < 4; i++) r[i] = fmaxf(v[i], 0.0f);
    return r;
}

__global__ void precompute_kernel(const float* __restrict__ twist,
                                  const float* __restrict__ init_p,
                                  const float* __restrict__ init_rpy,
                                  const float* __restrict__ W1, const float* __restrict__ b1,
                                  const float* __restrict__ W2, const float* __restrict__ b2,
                                  const float* __restrict__ W3, const float* __restrict__ b3,
                                  const float* __restrict__ W4, const float* __restrict__ b4,
                                  const float* __restrict__ W5, const float* __restrict__ b5,
                                  float* __restrict__ ws) {
    const int lane = threadIdx.x;       // 64 threads
    const int qd = lane >> 4, l16 = lane & 15;
    const f32x4 FZ = {0.f, 0.f, 0.f, 0.f};

    // ---- joint invariants + T0 (threads 0..12) ----
    if (lane < NJ) {
        int j = lane;
        float rho0 = twist[j*6+0], rho1 = twist[j*6+1], rho2 = twist[j*6+2];
        float w0   = twist[j*6+3], w1   = twist[j*6+4], w2   = twist[j*6+5];
        float wn = sqrtf(w0*w0 + w1*w1 + w2*w2 + 1e-12f);
        float inv = 1.0f / wn;
        float u0 = w0*inv, u1 = w1*inv, u2 = w2*inv;
        float ru0 = rho0*inv, ru1 = rho1*inv, ru2 = rho2*inv;
        float kru0 = u1*ru2 - u2*ru1;
        float kru1 = u2*ru0 - u0*ru2;
        float kru2 = u0*ru1 - u1*ru0;
        float ud = u0*ru0 + u1*ru1 + u2*ru2;
        float* o = ws + j*20;
        o[0] = wn;  o[1] = u0;  o[2] = u1;  o[3] = u2;
        o[4] = ru0; o[5] = ru1; o[6] = ru2;
        o[7] = kru0; o[8] = kru1; o[9] = kru2;
        o[10] = u0*ud - ru0; o[11] = u1*ud - ru1; o[12] = u2*ud - ru2;
        o[13] = u0*u0; o[14] = u0*u1; o[15] = u0*u2;
        o[16] = u1*u1; o[17] = u1*u2; o[18] = u2*u2;
    } else if (lane == NJ) {
        float r = init_rpy[0], p = init_rpy[1], y = init_rpy[2];
        float cr = cosf(r), sr = sinf(r);
        float cp = cosf(p), sp = sinf(p);
        float cy = cosf(y), sy = sinf(y);
        float* o = ws + NJ*20;
        o[0] = cy*cp; o[1] = cy*sp*sr - sy*cr; o[2] = cy*sp*cr + sy*sr;
        o[3] = sy*cp; o[4] = sy*sp*sr + cy*cr; o[5] = sy*sp*cr - cy*sr;
        o[6] = -sp;   o[7] = cp*sr;            o[8] = cp*cr;
        o[9] = init_p[0]; o[10] = init_p[1]; o[11] = init_p[2];
    }

    // ---- weight fragments (hi/lo split, lo UNSCALED residual) ----
    uint4* wf = (uint4*)(ws + WOFF);
    f32x4* bf = (f32x4*)(ws + BOFF);

    auto pack = [&](f32x4 w) -> uint4 {
        half4 h, l;
#pragma unroll
        for (int i = 0; i < 4; i++) {
            _Float16 hi = (_Float16)w[i];
            h[i] = hi;
            l[i] = (_Float16)(w[i] - (float)hi);
        }
        uint2 uh = __builtin_bit_cast(uint2, h);
        uint2 ul = __builtin_bit_cast(uint2, l);
        return make_uint4(uh.x, uh.y, ul.x, ul.y);
    };

    // f0: a1 (K=4 padded -> only qd==0 rows valid; k>=4 rows ZEROED so the
    // B-side x fragment never needs masking: 0 * finite = 0)
    {
        f32x4 w = ld4(W1 + l16*4);
        wf[0*64 + lane] = pack(qd == 0 ? w : FZ);
    }
    // f1,2: a2[ot]
    for (int ot = 0; ot < 2; ot++)
        wf[(1+ot)*64 + lane] = pack(ld4(W2 + (ot*16 + l16)*16 + 4*qd));
    // f3..10: a3[ot][kc]
    for (int ot = 0; ot < 4; ot++)
        for (int kc = 0; kc < 2; kc++)
            wf[(3 + ot*2 + kc)*64 + lane] = pack(ld4(W3 + (ot*16 + l16)*32 + kc*16 + 4*qd));
    // f11..18: a4[ot][kc]
    for (int ot = 0; ot < 2; ot++)
        for (int kc = 0; kc < 4; kc++)
            wf[(11 + ot*4 + kc)*64 + lane] = pack(ld4(W4 + (ot*16 + l16)*64 + kc*16 + 4*qd));
    // f19,20: a5[kc] (rows >=12 zeroed)
    {
        int r5 = (l16 < 12) ? l16 : 11;
        for (int kc = 0; kc < 2; kc++) {
            f32x4 w = ld4(W5 + r5*32 + kc*16 + 4*qd);
            wf[(19+kc)*64 + lane] = pack(l16 < 12 ? w : FZ);
        }
    }
    // bias frags
    bf[0*64 + lane] = ld4(b1 + 4*qd);
    for (int ot = 0; ot < 2; ot++) bf[(1+ot)*64 + lane] = ld4(b2 + ot*16 + 4*qd);
    for (int ot = 0; ot < 4; ot++) bf[(3+ot)*64 + lane] = ld4(b3 + ot*16 + 4*qd);
    for (int ot = 0; ot < 2; ot++) bf[(7+ot)*64 + lane] = ld4(b4 + ot*16 + 4*qd);
    {
        f32x4 w = ld4(b5 + ((qd < 3) ? 4*qd : 8));
        bf[9*64 + lane] = (qd < 3) ? w : FZ;
    }
}

// (256,2): the only spill-free cap for this structure (R4/R6/R8/R9/R11 all
// spilled at tighter caps — capped budgets split ~50/50 arch/AGPR and the arch
// half can't hold the live set). Latency attack is the K=32 2-MFMA chain below.
__global__ __launch_bounds__(256, 2) void fk_kernel(
    const float* __restrict__ mc,
    const float* __restrict__ ws,
    float* __restrict__ out) {
    const int tid = threadIdx.x;
    const int wv = tid >> 6, lane = tid & 63;
    const int qd = lane >> 4, l16 = lane & 15;
    const int wave_base = (blockIdx.x * 4 + wv) * 64;

    const uint4* wf = (const uint4*)(ws + WOFF);
    const f32x4* bf = (const f32x4*)(ws + BOFF);

    // LDS: 21 frags normal (21 KB) + 21 frags hi/lo-swapped (21 KB) + qbuf (13 KB)
    __shared__ __align__(16) uint4 wstage[21*64];
    __shared__ __align__(16) uint4 wstageS[21*64];
    __shared__ float qbuf[4][64*13];

    // stage weight frags once per block; build the swapped copy in the same pass
    for (int i = tid; i < 21*64; i += 256) {
        uint4 u = wf[i];
        wstage[i]  = u;
        wstageS[i] = make_uint4(u.z, u.w, u.x, u.y);   // [wl|wh]
    }

    __syncthreads();

    // Two independent 16-element chains (c=0,1) share each weight frag.
    // Per layer-step: acc = A_norm*B + acc ; acc = A_swap*B + acc  — full
    // double-f16 product in 2 dependent MFMAs (was 3 with K=16).
#pragma unroll 1
    for (int ep = 0; ep < 2; ep++) {
        const int ebase = wave_base + ep*32 + l16;

        half8 bx[2];
        bx[0] = split8(ld4(mc + (size_t)ebase * 4));
        bx[1] = split8(ld4(mc + (size_t)(ebase + 16) * 4));
        // no qd masking: a1 rows k>=4 are zero.

        // Layer 1: 4 -> 16
        half8 g1[2];
        {
            half8 an = __builtin_bit_cast(half8, wstage[0*64 + lane]);
            half8 as = __builtin_bit_cast(half8, wstageS[0*64 + lane]);
            f32x4 bv = bf[0*64 + lane];
#pragma unroll
            for (int c = 0; c < 2; c++) {
                f32x4 acc = bv;
                acc = MFMA32(an, bx[c], acc);
                acc = MFMA32(as, bx[c], acc);
                g1[c] = split8(relu4(acc));
            }
        }

        // Layer 2: 16 -> 32
        half8 g2[2][2];
#pragma unroll
        for (int ot = 0; ot < 2; ot++) {
            half8 an = __builtin_bit_cast(half8, wstage[(1+ot)*64 + lane]);
            half8 as = __builtin_bit_cast(half8, wstageS[(1+ot)*64 + lane]);
            f32x4 bv = bf[(1+ot)*64 + lane];
#pragma unroll
            for (int c = 0; c < 2; c++) {
                f32x4 acc = bv;
                acc = MFMA32(an, g1[c], acc);
                acc = MFMA32(as, g1[c], acc);
                g2[c][ot] = split8(relu4(acc));
            }
        }

        // Layer 3: 32 -> 64
        half8 g3[2][4];
#pragma unroll
        for (int ot = 0; ot < 4; ot++) {
            f32x4 bv = bf[(3+ot)*64 + lane];
            f32x4 acc[2];
#pragma unroll
            for (int c = 0; c < 2; c++) acc[c] = bv;
#pragma unroll
            for (int kc = 0; kc < 2; kc++) {
                half8 an = __builtin_bit_cast(half8, wstage[(3 + ot*2 + kc)*64 + lane]);
                half8 as = __builtin_bit_cast(half8, wstageS[(3 + ot*2 + kc)*64 + lane]);
#pragma unroll
                for (int c = 0; c < 2; c++) {
                    acc[c] = MFMA32(an, g2[c][kc], acc[c]);
                    acc[c] = MFMA32(as, g2[c][kc], acc[c]);
                }
            }
#pragma unroll
            for (int c = 0; c < 2; c++) g3[c][ot] = split8(relu4(acc[c]));
        }

        // Layer 4: 64 -> 32
        half8 g4[2][2];
#pragma unroll
        for (int ot = 0; ot < 2; ot++) {
            f32x4 bv = bf[(7+ot)*64 + lane];
            f32x4 acc[2];
#pragma unroll
            for (int c = 0; c < 2; c++) acc[c] = bv;
#pragma unroll
            for (int kc = 0; kc < 4; kc++) {
                half8 an = __builtin_bit_cast(half8, wstage[(11 + ot*4 + kc)*64 + lane]);
                half8 as = __builtin_bit_cast(half8, wstageS[(11 + ot*4 + kc)*64 + lane]);
#pragma unroll
                for (int c = 0; c < 2; c++) {
                    acc[c] = MFMA32(an, g3[c][kc], acc[c]);
                    acc[c] = MFMA32(as, g3[c][kc], acc[c]);
                }
            }
#pragma unroll
            for (int c = 0; c < 2; c++) g4[c][ot] = split8(relu4(acc[c]));
        }

        // Layer 5: 32 -> 12. C rows are 4*qd+i: qd 0..2 hold q[0..11]; qd==3
        // holds garbage rows 12..15 — with stride-13 qbuf its store would
        // clobber the next row's q[0..2], so mask it off.
        {
            f32x4 bv = bf[9*64 + lane];
            f32x4 acc[2];
#pragma unroll
            for (int c = 0; c < 2; c++) acc[c] = bv;
#pragma unroll
            for (int kc = 0; kc < 2; kc++) {
                half8 an = __builtin_bit_cast(half8, wstage[(19+kc)*64 + lane]);
                half8 as = __builtin_bit_cast(half8, wstageS[(19+kc)*64 + lane]);
#pragma unroll
                for (int c = 0; c < 2; c++) {
                    acc[c] = MFMA32(an, g4[c][kc], acc[c]);
                    acc[c] = MFMA32(as, g4[c][kc], acc[c]);
                }
            }
#pragma unroll
            for (int c = 0; c < 2; c++) {
                f32x4 qv = relu4(acc[c]);
                if (qd < 3) {
                    float* qb = &qbuf[wv][(ep*32 + c*16 + l16)*13 + 4*qd];
                    qb[0] = qv[0]; qb[1] = qv[1]; qb[2] = qv[2]; qb[3] = qv[3];
                }
            }
        }
    }

    // q writes are wave-private; drain LDS then redistribute
    asm volatile("s_waitcnt lgkmcnt(0)" ::: "memory");

    float qq[12];
#pragma unroll
    for (int j = 0; j < 12; j++) qq[j] = qbuf[wv][lane*13 + j];

    // ---------- FK chain (fp32) ----------
    const float* jc = ws;
    float M00 = 1.f, M01 = 0.f, M02 = 0.f;
    float M10 = 0.f, M11 = 1.f, M12 = 0.f;
    float M20 = 0.f, M21 = 0.f, M22 = 1.f;
    float v0 = 0.f, v1 = 0.f, v2 = 0.f;

#pragma unroll
    for (int j = 0; j < NJ; j++) {
        const float* c = jc + j*20;
        float wn = c[0];
        float u0 = c[1], u1 = c[2], u2 = c[3];
        float ru0 = c[4], ru1 = c[5], ru2 = c[6];
        float kru0 = c[7], kru1 = c[8], kru2 = c[9];
        float k2ru0 = c[10], k2ru1 = c[11], k2ru2 = c[12];
        float uu00 = c[13], uu01 = c[14], uu02 = c[15];
        float uu11 = c[16], uu12 = c[17], uu22 = c[18];

        float th = qq[j] * wn;
        float s = __sinf(th);
        float cth = __cosf(th);
        float cc = 1.0f - cth;
        float t = th - s;

        float R00 = 1.0f + cc*(uu00 - 1.0f);
        float R01 = cc*uu01 - s*u2;
        float R02 = cc*uu02 + s*u1;
        float R10 = cc*uu01 + s*u2;
        float R11 = 1.0f + cc*(uu11 - 1.0f);
        float R12 = cc*uu12 - s*u0;
        float R20 = cc*uu02 - s*u1;
        float R21 = cc*uu12 + s*u0;
        float R22 = 1.0f + cc*(uu22 - 1.0f);

        float p0 = th*ru0 + cc*kru0 + t*k2ru0;
        float p1 = th*ru1 + cc*kru1 + t*k2ru1;
        float p2 = th*ru2 + cc*kru2 + t*k2ru2;

        float n00 = M00*R00 + M01*R10 + M02*R20;
        float n01 = M00*R01 + M01*R11 + M02*R21;
        float n02 = M00*R02 + M01*R12 + M02*R22;
        float n10 = M10*R00 + M11*R10 + M12*R20;
        float n11 = M10*R01 + M11*R11 + M12*R21;
        float n12 = M10*R02 + M11*R12 + M12*R22;
        float n20 = M20*R00 + M21*R10 + M22*R20;
        float n21 = M20*R01 + M21*R11 + M22*R21;
        float n22 = M20*R02 + M21*R12 + M22*R22;
        v0 += M00*p0 + M01*p1 + M02*p2;
        v1 += M10*p0 + M11*p1 + M12*p2;
        v2 += M20*p0 + M21*p1 + M22*p2;
        M00 = n00; M01 = n01; M02 = n02;
        M10 = n10; M11 = n11; M12 = n12;
        M20 = n20; M21 = n21; M22 = n22;
    }

    const float* t0 = jc + NJ*20;
    float A00 = t0[0], A01 = t0[1], A02 = t0[2];
    float A10 = t0[3], A11 = t0[4], A12 = t0[5];
    float A20 = t0[6], A21 = t0[7], A22 = t0[8];
    float P0  = t0[9], P1  = t0[10], P2 = t0[11];

    float F00 = M00*A00 + M01*A10 + M02*A20;
    float F01 = M00*A01 + M01*A11 + M02*A21;
    float F02 = M00*A02 + M01*A12 + M02*A22;
    float F10 = M10*A00 + M11*A10 + M12*A20;
    float F11 = M10*A01 + M11*A11 + M12*A21;
    float F12 = M10*A02 + M11*A12 + M12*A22;
    float F20 = M20*A00 + M21*A10 + M22*A20;
    float F21 = M20*A01 + M21*A11 + M22*A21;
    float F22 = M20*A02 + M21*A12 + M22*A22;
    float Fv0 = M00*P0 + M01*P1 + M02*P2 + v0;
    float Fv1 = M10*P0 + M11*P1 + M12*P2 + v1;
    float Fv2 = M20*P0 + M21*P1 + M22*P2 + v2;

    const int eo = wave_base + lane;
    float4* o4 = (float4*)(out + (size_t)eo * 16);
    o4[0] = make_float4(F00, F01, F02, Fv0);
    o4[1] = make_float4(F10, F11, F12, Fv1);
    o4[2] = make_float4(F20, F21, F22, Fv2);
    o4[3] = make_float4(0.f, 0.f, 0.f, 1.f);
}

extern "C" void kernel_launch(void* const* d_in, const int* in_sizes, int n_in,
                              void* d_out, int out_size, void* d_ws, size_t ws_size,
                              hipStream_t stream) {
    const float* mc      = (const float*)d_in[0];
    const float* W1      = (const float*)d_in[1];
    const float* b1      = (const float*)d_in[2];
    const float* W2      = (const float*)d_in[3];
    const float* b2      = (const float*)d_in[4];
    const float* W3      = (const float*)d_in[5];
    const float* b3      = (const float*)d_in[6];
    const float* W4      = (const float*)d_in[7];
    const float* b4      = (const float*)d_in[8];
    const float* W5      = (const float*)d_in[9];
    const float* b5      = (const float*)d_in[10];
    const float* twist   = (const float*)d_in[11];
    const float* init_p  = (const float*)d_in[12];
    const float* init_rpy= (const float*)d_in[13];
    float* out = (float*)d_out;
    float* ws  = (float*)d_ws;

    precompute_kernel<<<1, 64, 0, stream>>>(twist, init_p, init_rpy,
                                            W1, b1, W2, b2, W3, b3, W4, b4, W5, b5, ws);
    fk_kernel<<<BATCH / 256, 256, 0, stream>>>(mc, ws, out);
}

// Round 13
// 138.341 us; speedup vs baseline: 1.0817x; 1.0272x over previous
//
#include <hip/hip_runtime.h>
#include <math.h>

#define BATCH 524288
#define NJ 12

// ws float layout:
//   [0..239]    joint consts (12 x 20)
//   [240..251]  T0 (R row-major 9, p 3)
//   [256..5631]     21 weight frags x 64 lanes x uint4 (h0..h3|l0..l3 packed f16, lo UNSCALED)
//   [5632..8191]    10 bias frags x 64 lanes x f32x4
#define WOFF 256
#define BOFF 5632

typedef _Float16 half4 __attribute__((ext_vector_type(4)));
typedef _Float16 half2t __attribute__((ext_vector_type(2)));
typedef float f32x4 __attribute__((ext_vector_type(4)));

#define MFMA16(a, b, c) __builtin_amdgcn_mfma_f32_16x16x16f16((a), (b), (c), 0, 0, 0)

__device__ __forceinline__ f32x4 ld4(const float* p) { return *(const f32x4*)p; }

// hi = RTZ f16 of v; lo = f16(v - hi), UNSCALED (residual below f16-normal is
// flushed with <=6e-5 abs error — inside budget; measured absmax 0.0078).
__device__ __forceinline__ void split4(f32x4 v, half4& h, half4& l) {
    half2t ha = __builtin_bit_cast(half2t, __builtin_amdgcn_cvt_pkrtz(v[0], v[1]));
    half2t hb = __builtin_bit_cast(half2t, __builtin_amdgcn_cvt_pkrtz(v[2], v[3]));
    float r0 = v[0] - (float)ha[0];
    float r1 = v[1] - (float)ha[1];
    float r2 = v[2] - (float)hb[0];
    float r3 = v[3] - (float)hb[1];
    half2t la = __builtin_bit_cast(half2t, __builtin_amdgcn_cvt_pkrtz(r0, r1));
    half2t lb = __builtin_bit_cast(half2t, __builtin_amdgcn_cvt_pkrtz(r2, r3));
    h = half4{ha[0], ha[1], hb[0], hb[1]};
    l = half4{la[0], la[1], lb[0], lb[1]};
}

__device__ __forceinline__ f32x4 relu4(f32x4 v) {
    f32x4 r;
#pragma unroll
    for (int i = 0; i < 4; i++) r[i] = fmaxf(v[i], 0.0f);
    return r;
}

__device__ __forceinline__ void unpack_frag(uint4 u, half4& h, half4& l) {
    uint2 a = make_uint2(u.x, u.y), b = make_uint2(u.z, u.w);
    h = __builtin_bit_cast(half4, a);
    l = __builtin_bit_cast(half4, b);
}

__global__ void precompute_kernel(const float* __restrict__ twist,
                                  const float* __restrict__ init_p,
                                  const float* __restrict__ init_rpy,
                                  const float* __restrict__ W1, const float* __restrict__ b1,
                                  const float* __restrict__ W2, const float* __restrict__ b2,
                                  const float* __restrict__ W3, const float* __restrict__ b3,
                                  const float* __restrict__ W4, const float* __restrict__ b4,
                                  const float* __restrict__ W5, const float* __restrict__ b5,
                                  float* __restrict__ ws) {
    const int lane = threadIdx.x;       // 64 threads
    const int qd = lane >> 4, l16 = lane & 15;
    const f32x4 FZ = {0.f, 0.f, 0.f, 0.f};

    // ---- joint invariants + T0 (threads 0..12) ----
    if (lane < NJ) {
        int j = lane;
        float rho0 = twist[j*6+0], rho1 = twist[j*6+1], rho2 = twist[j*6+2];
        float w0   = twist[j*6+3], w1   = twist[j*6+4], w2   = twist[j*6+5];
        float wn = sqrtf(w0*w0 + w1*w1 + w2*w2 + 1e-12f);
        float inv = 1.0f / wn;
        float u0 = w0*inv, u1 = w1*inv, u2 = w2*inv;
        float ru0 = rho0*inv, ru1 = rho1*inv, ru2 = rho2*inv;
        float kru0 = u1*ru2 - u2*ru1;
        float kru1 = u2*ru0 - u0*ru2;
        float kru2 = u0*ru1 - u1*ru0;
        float ud = u0*ru0 + u1*ru1 + u2*ru2;
        float* o = ws + j*20;
        o[0] = wn;  o[1] = u0;  o[2] = u1;  o[3] = u2;
        o[4] = ru0; o[5] = ru1; o[6] = ru2;
        o[7] = kru0; o[8] = kru1; o[9] = kru2;
        o[10] = u0*ud - ru0; o[11] = u1*ud - ru1; o[12] = u2*ud - ru2;
        o[13] = u0*u0; o[14] = u0*u1; o[15] = u0*u2;
        o[16] = u1*u1; o[17] = u1*u2; o[18] = u2*u2;
    } else if (lane == NJ) {
        float r = init_rpy[0], p = init_rpy[1], y = init_rpy[2];
        float cr = cosf(r), sr = sinf(r);
        float cp = cosf(p), sp = sinf(p);
        float cy = cosf(y), sy = sinf(y);
        float* o = ws + NJ*20;
        o[0] = cy*cp; o[1] = cy*sp*sr - sy*cr; o[2] = cy*sp*cr + sy*sr;
        o[3] = sy*cp; o[4] = sy*sp*sr + cy*cr; o[5] = sy*sp*cr - cy*sr;
        o[6] = -sp;   o[7] = cp*sr;            o[8] = cp*cr;
        o[9] = init_p[0]; o[10] = init_p[1]; o[11] = init_p[2];
    }

    // ---- weight fragments (hi/lo split, lo UNSCALED residual) ----
    uint4* wf = (uint4*)(ws + WOFF);
    f32x4* bf = (f32x4*)(ws + BOFF);

    auto pack = [&](f32x4 w) -> uint4 {
        half4 h, l;
#pragma unroll
        for (int i = 0; i < 4; i++) {
            _Float16 hi = (_Float16)w[i];
            h[i] = hi;
            l[i] = (_Float16)(w[i] - (float)hi);
        }
        uint2 uh = __builtin_bit_cast(uint2, h);
        uint2 ul = __builtin_bit_cast(uint2, l);
        return make_uint4(uh.x, uh.y, ul.x, ul.y);
    };

    // f0: a1 (K=4 padded -> only qd==0 rows valid; k>=4 rows ZEROED so the
    // B-side x fragment never needs masking: 0 * finite = 0)
    {
        f32x4 w = ld4(W1 + l16*4);
        wf[0*64 + lane] = pack(qd == 0 ? w : FZ);
    }
    // f1,2: a2[ot]
    for (int ot = 0; ot < 2; ot++)
        wf[(1+ot)*64 + lane] = pack(ld4(W2 + (ot*16 + l16)*16 + 4*qd));
    // f3..10: a3[ot][kc]
    for (int ot = 0; ot < 4; ot++)
        for (int kc = 0; kc < 2; kc++)
            wf[(3 + ot*2 + kc)*64 + lane] = pack(ld4(W3 + (ot*16 + l16)*32 + kc*16 + 4*qd));
    // f11..18: a4[ot][kc]
    for (int ot = 0; ot < 2; ot++)
        for (int kc = 0; kc < 4; kc++)
            wf[(11 + ot*4 + kc)*64 + lane] = pack(ld4(W4 + (ot*16 + l16)*64 + kc*16 + 4*qd));
    // f19,20: a5[kc] (rows >=12 zeroed)
    {
        int r5 = (l16 < 12) ? l16 : 11;
        for (int kc = 0; kc < 2; kc++) {
            f32x4 w = ld4(W5 + r5*32 + kc*16 + 4*qd);
            wf[(19+kc)*64 + lane] = pack(l16 < 12 ? w : FZ);
        }
    }
    // bias frags
    bf[0*64 + lane] = ld4(b1 + 4*qd);
    for (int ot = 0; ot < 2; ot++) bf[(1+ot)*64 + lane] = ld4(b2 + ot*16 + 4*qd);
    for (int ot = 0; ot < 4; ot++) bf[(3+ot)*64 + lane] = ld4(b3 + ot*16 + 4*qd);
    for (int ot = 0; ot < 2; ot++) bf[(7+ot)*64 + lane] = ld4(b4 + ot*16 + 4*qd);
    {
        f32x4 w = ld4(b5 + ((qd < 3) ? 4*qd : 8));
        bf[9*64 + lane] = (qd < 3) ? w : FZ;
    }
}

// Single-chain, UNCAPPED allocation ((256,2) floor is non-binding): launch-bounds
// caps poison the allocator (50/50 arch/AGPR split: R4/R6/R8/R9/R11 all spilled).
// The single-chain live set (~60-90 arch) should let combined regs land <=170,
// naturally giving 3 waves/SIMD — TLP instead of the 2-chain's ILP.
__global__ __launch_bounds__(256, 2) void fk_kernel(
    const float* __restrict__ mc,
    const float* __restrict__ ws,
    float* __restrict__ out) {
    const int tid = threadIdx.x;
    const int wv = tid >> 6, lane = tid & 63;
    const int qd = lane >> 4, l16 = lane & 15;
    const int wave_base = (blockIdx.x * 4 + wv) * 64;

    const uint4* wf = (const uint4*)(ws + WOFF);
    const f32x4* bf = (const f32x4*)(ws + BOFF);

    // LDS: 21 weight frags (21 KB) + per-wave q buffer (stride 13, ~13 KB)
    __shared__ __align__(16) uint4 wstage[21*64];
    __shared__ float qbuf[4][64*13];

    for (int i = tid; i < 21*64; i += 256) wstage[i] = wf[i];

    __syncthreads();

    f32x4 xcur = ld4(mc + (size_t)(wave_base + l16) * 4);

#pragma unroll 1
    for (int e = 0; e < 4; e++) {
        f32x4 xnext;
        if (e < 3) xnext = ld4(mc + (size_t)(wave_base + (e+1)*16 + l16) * 4);

        // Layer 1: 4 -> 16. x B-frag needs no qd masking: A rows k>=4 are zero.
        half4 bxh, bxl; split4(xcur, bxh, bxl);
        half4 g1h, g1l;
        {
            half4 wh, wl; unpack_frag(wstage[0*64 + lane], wh, wl);
            f32x4 acc = bf[0*64 + lane];
            acc = MFMA16(wh, bxh, acc);
            acc = MFMA16(wh, bxl, acc);
            acc = MFMA16(wl, bxh, acc);
            split4(relu4(acc), g1h, g1l);
        }

        // Layer 2: 16 -> 32
        half4 g2h[2], g2l[2];
#pragma unroll
        for (int ot = 0; ot < 2; ot++) {
            half4 wh, wl; unpack_frag(wstage[(1+ot)*64 + lane], wh, wl);
            f32x4 acc = bf[(1+ot)*64 + lane];
            acc = MFMA16(wh, g1h, acc);
            acc = MFMA16(wh, g1l, acc);
            acc = MFMA16(wl, g1h, acc);
            split4(relu4(acc), g2h[ot], g2l[ot]);
        }

        // Layer 3: 32 -> 64
        half4 g3h[4], g3l[4];
#pragma unroll
        for (int ot = 0; ot < 4; ot++) {
            f32x4 acc = bf[(3+ot)*64 + lane];
#pragma unroll
            for (int kc = 0; kc < 2; kc++) {
                half4 wh, wl; unpack_frag(wstage[(3 + ot*2 + kc)*64 + lane], wh, wl);
                acc = MFMA16(wh, g2h[kc], acc);
                acc = MFMA16(wh, g2l[kc], acc);
                acc = MFMA16(wl, g2h[kc], acc);
            }
            split4(relu4(acc), g3h[ot], g3l[ot]);
        }

        // Layer 4: 64 -> 32
        half4 g4h[2], g4l[2];
#pragma unroll
        for (int ot = 0; ot < 2; ot++) {
            f32x4 acc = bf[(7+ot)*64 + lane];
#pragma unroll
            for (int kc = 0; kc < 4; kc++) {
                half4 wh, wl; unpack_frag(wstage[(11 + ot*4 + kc)*64 + lane], wh, wl);
                acc = MFMA16(wh, g3h[kc], acc);
                acc = MFMA16(wh, g3l[kc], acc);
                acc = MFMA16(wl, g3h[kc], acc);
            }
            split4(relu4(acc), g4h[ot], g4l[ot]);
        }

        // Layer 5: 32 -> 12. C rows are 4*qd+i: qd 0..2 hold q[0..11]; qd==3 holds
        // garbage rows 12..15 — with stride-13 qbuf its store would clobber the
        // next row's q[0..2], so mask it off.
        {
            f32x4 acc = bf[9*64 + lane];
#pragma unroll
            for (int kc = 0; kc < 2; kc++) {
                half4 wh, wl; unpack_frag(wstage[(19+kc)*64 + lane], wh, wl);
                acc = MFMA16(wh, g4h[kc], acc);
                acc = MFMA16(wh, g4l[kc], acc);
                acc = MFMA16(wl, g4h[kc], acc);
            }
            f32x4 qv = relu4(acc);
            if (qd < 3) {
                float* qb = &qbuf[wv][(e*16 + l16)*13 + 4*qd];
                qb[0] = qv[0]; qb[1] = qv[1]; qb[2] = qv[2]; qb[3] = qv[3];
            }
        }
        xcur = xnext;
    }

    // q writes are wave-private; drain LDS then redistribute
    asm volatile("s_waitcnt lgkmcnt(0)" ::: "memory");

    float qq[12];
#pragma unroll
    for (int j = 0; j < 12; j++) qq[j] = qbuf[wv][lane*13 + j];

    // ---------- FK chain (fp32) ----------
    const float* jc = ws;
    float M00 = 1.f, M01 = 0.f, M02 = 0.f;
    float M10 = 0.f, M11 = 1.f, M12 = 0.f;
    float M20 = 0.f, M21 = 0.f, M22 = 1.f;
    float v0 = 0.f, v1 = 0.f, v2 = 0.f;

#pragma unroll
    for (int j = 0; j < NJ; j++) {
        const float* c = jc + j*20;
        float wn = c[0];
        float u0 = c[1], u1 = c[2], u2 = c[3];
        float ru0 = c[4], ru1 = c[5], ru2 = c[6];
        float kru0 = c[7], kru1 = c[8], kru2 = c[9];
        float k2ru0 = c[10], k2ru1 = c[11], k2ru2 = c[12];
        float uu00 = c[13], uu01 = c[14], uu02 = c[15];
        float uu11 = c[16], uu12 = c[17], uu22 = c[18];

        float th = qq[j] * wn;
        float s = __sinf(th);
        float cth = __cosf(th);
        float cc = 1.0f - cth;
        float t = th - s;

        float R00 = 1.0f + cc*(uu00 - 1.0f);
        float R01 = cc*uu01 - s*u2;
        float R02 = cc*uu02 + s*u1;
        float R10 = cc*uu01 + s*u2;
        float R11 = 1.0f + cc*(uu11 - 1.0f);
        float R12 = cc*uu12 - s*u0;
        float R20 = cc*uu02 - s*u1;
        float R21 = cc*uu12 + s*u0;
        float R22 = 1.0f + cc*(uu22 - 1.0f);

        float p0 = th*ru0 + cc*kru0 + t*k2ru0;
        float p1 = th*ru1 + cc*kru1 + t*k2ru1;
        float p2 = th*ru2 + cc*kru2 + t*k2ru2;

        float n00 = M00*R00 + M01*R10 + M02*R20;
        float n01 = M00*R01 + M01*R11 + M02*R21;
        float n02 = M00*R02 + M01*R12 + M02*R22;
        float n10 = M10*R00 + M11*R10 + M12*R20;
        float n11 = M10*R01 + M11*R11 + M12*R21;
        float n12 = M10*R02 + M11*R12 + M12*R22;
        float n20 = M20*R00 + M21*R10 + M22*R20;
        float n21 = M20*R01 + M21*R11 + M22*R21;
        float n22 = M20*R02 + M21*R12 + M22*R22;
        v0 += M00*p0 + M01*p1 + M02*p2;
        v1 += M10*p0 + M11*p1 + M12*p2;
        v2 += M20*p0 + M21*p1 + M22*p2;
        M00 = n00; M01 = n01; M02 = n02;
        M10 = n10; M11 = n11; M12 = n12;
        M20 = n20; M21 = n21; M22 = n22;
    }

    const float* t0 = jc + NJ*20;
    float A00 = t0[0], A01 = t0[1], A02 = t0[2];
    float A10 = t0[3], A11 = t0[4], A12 = t0[5];
    float A20 = t0[6], A21 = t0[7], A22 = t0[8];
    float P0  = t0[9], P1  = t0[10], P2 = t0[11];

    float F00 = M00*A00 + M01*A10 + M02*A20;
    float F01 = M00*A01 + M01*A11 + M02*A21;
    float F02 = M00*A02 + M01*A12 + M02*A22;
    float F10 = M10*A00 + M11*A10 + M12*A20;
    float F11 = M10*A01 + M11*A11 + M12*A21;
    float F12 = M10*A02 + M11*A12 + M12*A22;
    float F20 = M20*A00 + M21*A10 + M22*A20;
    float F21 = M20*A01 + M21*A11 + M22*A21;
    float F22 = M20*A02 + M21*A12 + M22*A22;
    float Fv0 = M00*P0 + M01*P1 + M02*P2 + v0;
    float Fv1 = M10*P0 + M11*P1 + M12*P2 + v1;
    float Fv2 = M20*P0 + M21*P1 + M22*P2 + v2;

    const int eo = wave_base + lane;
    float4* o4 = (float4*)(out + (size_t)eo * 16);
    o4[0] = make_float4(F00, F01, F02, Fv0);
    o4[1] = make_float4(F10, F11, F12, Fv1);
    o4[2] = make_float4(F20, F21, F22, Fv2);
    o4[3] = make_float4(0.f, 0.f, 0.f, 1.f);
}

extern "C" void kernel_launch(void* const* d_in, const int* in_sizes, int n_in,
                              void* d_out, int out_size, void* d_ws, size_t ws_size,
                              hipStream_t stream) {
    const float* mc      = (const float*)d_in[0];
    const float* W1      = (const float*)d_in[1];
    const float* b1      = (const float*)d_in[2];
    const float* W2      = (const float*)d_in[3];
    const float* b2      = (const float*)d_in[4];
    const float* W3      = (const float*)d_in[5];
    const float* b3      = (const float*)d_in[6];
    const float* W4      = (const float*)d_in[7];
    const float* b4      = (const float*)d_in[8];
    const float* W5      = (const float*)d_in[9];
    const float* b5      = (const float*)d_in[10];
    const float* twist   = (const float*)d_in[11];
    const float* init_p  = (const float*)d_in[12];
    const float* init_rpy= (const float*)d_in[13];
    float* out = (float*)d_out;
    float* ws  = (float*)d_ws;

    precompute_kernel<<<1, 64, 0, stream>>>(twist, init_p, init_rpy,
                                            W1, b1, W2, b2, W3, b3, W4, b4, W5, b5, ws);
    fk_kernel<<<BATCH / 256, 256, 0, stream>>>(mc, ws, out);
}